// Round 11
// baseline (74.754 us; speedup 1.0000x reference)
//
#include <hip/hip_runtime.h>
#include <hip/hip_cooperative_groups.h>
#include <math.h>

namespace cg = cooperative_groups;

#define BB   4      // batch
#define HH   32     // query heads
#define GG   4      // query groups (also KV heads)
#define HPG  8      // heads per group
#define DD   128    // head dim
#define NCK  128    // number of compressed keys per head
#define SEQ  8192   // key/value sequence length
#define NSEL 16     // selected blocks
#define BLK  64     // block size

// Single cooperative kernel, 1024 blocks x 256 threads (4 blocks/CU, co-resident).
// Phase 1: GEMV — block bid handles bh = bid>>3, 16 rows; 16 lanes/row, coalesced.
// grid.sync()
// Phase 2: R10's select+gather — block bid = (bg, s, half, K/V), trimmed softmax
//          + rank selection + 16 KB copy.
__global__ __launch_bounds__(256, 4) void fused_coop_kernel(
    const float* __restrict__ query,
    const float* __restrict__ ck,
    const float* __restrict__ keys,
    const float* __restrict__ values,
    float* __restrict__ scores,      // ws: 4*32*128 floats
    float* __restrict__ out)
{
    const int bid = blockIdx.x;      // 0..1023
    const int t   = threadIdx.x;     // 0..255

    __shared__ float q_sh[DD];
    __shared__ float reds[2][HPG];
    __shared__ float pm[NCK];
    __shared__ int   sel_sh;

    // ---------------- phase 1: GEMV ----------------
    {
        const int bh   = bid >> 3;             // 0..127
        const int r    = (bid & 7) * 16 + (t >> 4);  // row 0..127
        const int lane = t & 15;

        if (t < DD) q_sh[t] = query[(size_t)bh * DD + t];
        __syncthreads();

        const float4* c4 = (const float4*)(ck + ((size_t)bh * NCK + r) * DD) + lane;
        const float4* q4 = ((const float4*)q_sh) + lane;
        float s = 0.0f;
        #pragma unroll
        for (int i = 0; i < 2; ++i) {
            float4 a = q4[i * 16];
            float4 c = c4[i * 16];             // 16 lanes -> contiguous 256 B
            s += a.x * c.x + a.y * c.y + a.z * c.z + a.w * c.w;
        }
        s += __shfl_xor(s, 1);
        s += __shfl_xor(s, 2);
        s += __shfl_xor(s, 4);
        s += __shfl_xor(s, 8);                 // identical on the row's 16 lanes

        if (lane == 0) scores[(size_t)bh * NCK + r] = s * 0.08838834764831845f;
    }

    cg::this_grid().sync();

    // ---------------- phase 2: select + gather ----------------
    const int q2   = bid & 3;
    const int isV  = q2 >> 1;
    const int half = q2 & 1;
    const int s    = (bid >> 2) & 15;          // rank this block copies
    const int bg   = bid >> 6;                 // 0..15
    const int b    = bg >> 2;
    const int g    = bg & 3;
    const int w    = t >> 6;                   // wave 0..3 (softmax uses 0,1)

    float e[HPG];

    if (t < NCK) {
        #pragma unroll
        for (int j = 0; j < HPG; ++j)
            e[j] = expf(scores[(size_t)(b * HH + g * HPG + j) * NCK + t]);
        #pragma unroll
        for (int j = 0; j < HPG; ++j) {
            float ssum = e[j];                 // wave butterfly: per-head partial sum
            #pragma unroll
            for (int off = 1; off < 64; off <<= 1) ssum += __shfl_xor(ssum, off);
            if ((t & 63) == 0) reds[w][j] = ssum;
        }
    }
    __syncthreads();

    if (t < NCK) {
        float p = 0.0f;
        #pragma unroll
        for (int j = 0; j < HPG; ++j) p += e[j] / (reds[0][j] + reds[1][j]);
        pm[t] = p;                             // mean scaling dropped: rank-invariant
    }
    __syncthreads();

    // rank of row t (stable descending = lax.top_k order)
    if (t < NCK) {
        const float mv = pm[t];
        int rank = 0;
        for (int i = 0; i < NCK; ++i) {
            const float vi = pm[i];            // uniform index -> LDS broadcast
            if (vi > mv || (vi == mv && i < t)) ++rank;
        }
        if (rank == s) sel_sh = t;             // exactly one thread matches
    }
    __syncthreads();
    const int sel = sel_sh;

    // copy a 32x128 half-block: 1024 float4, 256 threads -> 4 each
    const size_t src  = ((size_t)bg * SEQ + (size_t)sel * BLK + half * 32) * DD;
    const size_t dst  = ((size_t)bg * (NSEL * BLK) + (size_t)s * BLK + half * 32) * DD;
    const size_t VOFF = (size_t)BB * GG * NSEL * BLK * DD;

    const float4* sp = (const float4*)((isV ? values : keys) + src);
    float4*       dp = (float4*)(out + (isV ? VOFF : 0) + dst);

    #pragma unroll
    for (int i = 0; i < 4; ++i) dp[i * 256 + t] = sp[i * 256 + t];
}

extern "C" void kernel_launch(void* const* d_in, const int* in_sizes, int n_in,
                              void* d_out, int out_size, void* d_ws, size_t ws_size,
                              hipStream_t stream) {
    const float* query  = (const float*)d_in[0];   // (4,32,1,128)
    const float* ck     = (const float*)d_in[1];   // (4,32,128,128)
    const float* keys   = (const float*)d_in[2];   // (4,4,8192,128)
    const float* values = (const float*)d_in[3];   // (4,4,8192,128)
    float* out    = (float*)d_out;
    float* scores = (float*)d_ws;                  // 64 KB

    void* args[] = { (void*)&query, (void*)&ck, (void*)&keys, (void*)&values,
                     (void*)&scores, (void*)&out };
    hipLaunchCooperativeKernel((const void*)fused_coop_kernel,
                               dim3(BB * GG * NSEL * 4), dim3(256),
                               args, 0, stream);
}

// Round 12
// 18.449 us; speedup vs baseline: 4.0520x; 4.0520x over previous
//
#include <hip/hip_runtime.h>
#include <math.h>

#define BB   4      // batch
#define HH   32     // query heads
#define GG   4      // query groups (also KV heads)
#define HPG  8      // heads per group
#define DD   128    // head dim
#define NCK  128    // number of compressed keys per head
#define SEQ  8192   // key/value sequence length
#define NSEL 16     // selected blocks
#define BLK  64     // block size

// Kernel 1: GEMV + exp + deterministic partial exp-sums.
// One block per (b,h,half): 64 rows x 8 lanes/row, coalesced.
// Writes e = exp(scaled score) per row and one partial sum per (bh,half).
__global__ __launch_bounds__(512, 1) void gemv_exp_kernel(const float* __restrict__ query,
                                                          const float* __restrict__ ck,
                                                          float* __restrict__ e_out,
                                                          float* __restrict__ psum_out) {
    const int blk  = blockIdx.x;         // 0..255
    const int bh   = blk >> 1;           // 0..127
    const int half = blk & 1;
    const int t    = threadIdx.x;        // 0..511
    const int r    = (t >> 3) + half * 64;
    const int sub  = t & 7;
    const int w    = t >> 6;             // wave 0..7

    __shared__ float q_sh[DD];
    __shared__ float wred[8];

    if (t < DD) q_sh[t] = query[(size_t)bh * DD + t];
    __syncthreads();

    const float4* c4 = (const float4*)(ck + ((size_t)bh * NCK + r) * DD) + sub;
    const float4* q4 = ((const float4*)q_sh) + sub;
    float s = 0.0f;
    #pragma unroll
    for (int i = 0; i < 4; ++i) {
        float4 a = q4[i * 8];
        float4 c = c4[i * 8];            // 8 lanes -> contiguous 128 B line
        s += a.x * c.x + a.y * c.y + a.z * c.z + a.w * c.w;
    }
    s += __shfl_xor(s, 1);
    s += __shfl_xor(s, 2);
    s += __shfl_xor(s, 4);               // identical on the row's 8 lanes

    const float e = expf(s * 0.08838834764831845f);   // no-max exp: scores ~N(0,1)
    if (sub == 0) e_out[(size_t)bh * NCK + r] = e;

    // wave butterfly: each wave holds 8 rows x8 dup -> bsum = 8 * (sum of 8 rows)
    float bsum = e;
    #pragma unroll
    for (int off = 1; off < 64; off <<= 1) bsum += __shfl_xor(bsum, off);
    if ((t & 63) == 0) wred[w] = bsum * 0.125f;       // exact /8
    __syncthreads();

    if (t == 0) {
        float p = 0.0f;
        #pragma unroll
        for (int i = 0; i < 8; ++i) p += wred[i];     // fixed order: deterministic
        psum_out[bh * 2 + half] = p;
    }
}

// Kernel 2: one block per (bg, s, half, K-or-V) = 1024 blocks x 256 threads.
// Minimal prefix: load e + precomputed sums, rank selection, 16 KB copy.
__global__ __launch_bounds__(256, 1) void select_gather_kernel(const float* __restrict__ e_in,
                                                               const float* __restrict__ psum,
                                                               const float* __restrict__ keys,
                                                               const float* __restrict__ values,
                                                               float* __restrict__ out) {
    const int bid  = blockIdx.x;         // 0..1023
    const int q2   = bid & 3;
    const int isV  = q2 >> 1;
    const int half = q2 & 1;
    const int s    = (bid >> 2) & 15;    // rank this block copies
    const int bg   = bid >> 6;           // 0..15
    const int b    = bg >> 2;
    const int g    = bg & 3;
    const int t    = threadIdx.x;        // 0..255

    __shared__ float pm[NCK];
    __shared__ int   sel_sh;

    if (t < NCK) {
        const int base = b * HH + g * HPG;
        float p = 0.0f;
        #pragma unroll
        for (int j = 0; j < HPG; ++j) {
            const float ej = e_in[(size_t)(base + j) * NCK + t];
            const float sj = psum[(base + j) * 2] + psum[(base + j) * 2 + 1]; // scalar
            p += ej / sj;
        }
        pm[t] = p;                        // mean scaling dropped: rank-invariant
    }
    __syncthreads();

    // rank of row t (stable descending = lax.top_k order)
    if (t < NCK) {
        const float mv = pm[t];
        int rank = 0;
        for (int i = 0; i < NCK; ++i) {
            const float vi = pm[i];       // uniform index -> LDS broadcast
            if (vi > mv || (vi == mv && i < t)) ++rank;
        }
        if (rank == s) sel_sh = t;        // exactly one thread matches
    }
    __syncthreads();
    const int sel = sel_sh;

    // copy a 32x128 half-block: 1024 float4, 256 threads -> 4 each
    const size_t src  = ((size_t)bg * SEQ + (size_t)sel * BLK + half * 32) * DD;
    const size_t dst  = ((size_t)bg * (NSEL * BLK) + (size_t)s * BLK + half * 32) * DD;
    const size_t VOFF = (size_t)BB * GG * NSEL * BLK * DD;

    const float4* sp = (const float4*)((isV ? values : keys) + src);
    float4*       dp = (float4*)(out + (isV ? VOFF : 0) + dst);

    #pragma unroll
    for (int i = 0; i < 4; ++i) dp[i * 256 + t] = sp[i * 256 + t];
}

extern "C" void kernel_launch(void* const* d_in, const int* in_sizes, int n_in,
                              void* d_out, int out_size, void* d_ws, size_t ws_size,
                              hipStream_t stream) {
    const float* query  = (const float*)d_in[0];   // (4,32,1,128)
    const float* ck     = (const float*)d_in[1];   // (4,32,128,128)
    const float* keys   = (const float*)d_in[2];   // (4,4,8192,128)
    const float* values = (const float*)d_in[3];   // (4,4,8192,128)
    float* out = (float*)d_out;

    float* e_ws   = (float*)d_ws;                                   // 64 KB
    float* ps_ws  = (float*)((char*)d_ws + (size_t)BB * HH * NCK * sizeof(float)); // 1 KB

    gemv_exp_kernel<<<BB * HH * 2, 512, 0, stream>>>(query, ck, e_ws, ps_ws);
    select_gather_kernel<<<BB * GG * NSEL * 4, 256, 0, stream>>>(e_ws, ps_ws, keys, values, out);
}